// Round 2
// baseline (447.961 us; speedup 1.0000x reference)
//
#include <hip/hip_runtime.h>

// Problem constants (fixed by the reference setup)
constexpr int  N_IN  = 50000;
constexpr int  C     = 64;
constexpr int  T     = 8;
constexpr long long E = 800000;
constexpr int  N_OUT = 50000;
constexpr int  F     = 64;

// ---------------------------------------------------------------------------
// K0: initialize out[o*64+f] = bias[f]  (d_out is poisoned 0xAA before launch)
// ---------------------------------------------------------------------------
__global__ __launch_bounds__(256) void init_out_kernel(float* __restrict__ out,
                                                       const float* __restrict__ bias) {
    int idx = blockIdx.x * 256 + threadIdx.x;
    if (idx < N_OUT * F) out[idx] = bias[idx & (F - 1)];
}

// ---------------------------------------------------------------------------
// K1: proj[i, t, f] = sum_c nf[i,c] * K[t,c,f]
//   grid = (ceil(N_IN/256), T), block = 256
//   Each thread: one node i, one t, all 64 f.
//   K_t (16 KB) staged in LDS; inner reads are wave-uniform -> LDS broadcast.
//   f blocked by 4 so K reads become ds_read_b128.
// ---------------------------------------------------------------------------
__global__ __launch_bounds__(256) void project_kernel(const float* __restrict__ nf,
                                                      const float* __restrict__ Kmat,
                                                      float* __restrict__ proj) {
    __shared__ float Ks[C * F];  // 16 KB

    const int t = blockIdx.y;
    const int i = blockIdx.x * 256 + threadIdx.x;

    // cooperative load of K_t: 4096 floats via float4, fully coalesced
    const float4* Kg  = (const float4*)(Kmat + (long long)t * C * F);
    float4*       Ks4 = (float4*)Ks;
#pragma unroll
    for (int k = 0; k < 4; ++k) Ks4[k * 256 + threadIdx.x] = Kg[k * 256 + threadIdx.x];
    __syncthreads();

    if (i >= N_IN) return;

    // node row into registers (16 x float4)
    float reg[C];
    const float4* row = (const float4*)(nf + (long long)i * C);
#pragma unroll
    for (int k = 0; k < 16; ++k) {
        float4 v = row[k];
        reg[4 * k + 0] = v.x; reg[4 * k + 1] = v.y;
        reg[4 * k + 2] = v.z; reg[4 * k + 3] = v.w;
    }

    float4* out4 = (float4*)(proj + (long long)i * (T * F) + (long long)t * F);
#pragma unroll
    for (int fg = 0; fg < F / 4; ++fg) {
        float4 acc = {0.f, 0.f, 0.f, 0.f};
#pragma unroll
        for (int c = 0; c < C; ++c) {
            float4 kv = *(const float4*)(Ks + c * F + fg * 4);  // broadcast, b128
            acc.x += reg[c] * kv.x;
            acc.y += reg[c] * kv.y;
            acc.z += reg[c] * kv.z;
            acc.w += reg[c] * kv.w;
        }
        out4[fg] = acc;
    }
}

// ---------------------------------------------------------------------------
// K2: per edge e (one wave, lane = f):
//   acc_f = sum_t ef[t,e] * proj[idx_in[e], t, f]
//   atomicAdd(out[idx_out[e]*64 + f], acc_f)
//
// indices are int32 on device (JAX int64 -> int32 without x64; harness
// contract: "integer -> const int*"). Layout (E,2): [2e]=out, [2e+1]=in.
// ---------------------------------------------------------------------------
__global__ __launch_bounds__(256) void edge_scatter_kernel(const float* __restrict__ ef,
                                                           const int* __restrict__ idx,
                                                           const float* __restrict__ proj,
                                                           float* __restrict__ out) {
    const long long e = (long long)blockIdx.x * 4 + (threadIdx.x >> 6);
    const int lane = threadIdx.x & 63;
    if (e >= E) return;

    const int o = idx[2 * e];      // segment id (output node)
    const int i = idx[2 * e + 1];  // gather id (input node)

    const float* p = proj + (long long)i * (T * F) + lane;

    float acc = 0.f;
#pragma unroll
    for (int t = 0; t < T; ++t) {
        float w = ef[(long long)t * E + e];  // same addr across wave -> 1 txn
        acc += w * p[t * F];                 // coalesced 256 B per t
    }

    atomicAdd(out + (long long)o * F + lane, acc);  // 64 consecutive floats
}

// ---------------------------------------------------------------------------
extern "C" void kernel_launch(void* const* d_in, const int* in_sizes, int n_in,
                              void* d_out, int out_size, void* d_ws, size_t ws_size,
                              hipStream_t stream) {
    const float* nf   = (const float*)d_in[0];  // (N_IN, C)
    const float* ef   = (const float*)d_in[1];  // (T, E)
    const int*   idx  = (const int*)d_in[2];    // (E, 2) int32 on device
    const float* Kmat = (const float*)d_in[3];  // (T, C, F)
    const float* bias = (const float*)d_in[4];  // (F,)
    float*       out  = (float*)d_out;          // (N_OUT, F)

    float* proj = (float*)d_ws;  // (N_IN, T, F) = 102.4 MB

    // K0: out = bias
    init_out_kernel<<<(N_OUT * F + 255) / 256, 256, 0, stream>>>(out, bias);

    // K1: projection
    dim3 pgrid((N_IN + 255) / 256, T);
    project_kernel<<<pgrid, 256, 0, stream>>>(nf, Kmat, proj);

    // K2: gather + t-reduce + scatter-add
    const int edges_per_block = 4;  // 4 waves of 64
    edge_scatter_kernel<<<(int)((E + edges_per_block - 1) / edges_per_block), 256, 0, stream>>>(
        ef, idx, proj, out);
}